// Round 8
// baseline (286.755 us; speedup 1.0000x reference)
//
#include <hip/hip_runtime.h>
#include <math.h>

// Problem constants
constexpr int Bc = 2;
constexpr int Sc = 2048;
constexpr int Dc = 1024;
constexpr int Hc = 16;
constexpr int HDc = 64;

// Q pre-scale: attention 1/sqrt(64) folded with log2(e) for exp2-domain softmax
constexpr float QSC = 0.125f * 1.4426950408889634f;

typedef __attribute__((ext_vector_type(8))) short bf16x8;
typedef __attribute__((ext_vector_type(4))) short bf16x4;
typedef __attribute__((ext_vector_type(4))) float f32x4;
typedef __attribute__((ext_vector_type(4))) unsigned short us4;
typedef __attribute__((ext_vector_type(2))) unsigned int u32x2;

// K=16 bf16 MFMA (A/B = 4 bf16): builtin name varies; hedge + asm fallback.
#if __has_builtin(__builtin_amdgcn_mfma_f32_16x16x16bf16_1k)
__device__ __forceinline__ f32x4 mfma16(bf16x4 a, bf16x4 b, f32x4 c) {
    return __builtin_amdgcn_mfma_f32_16x16x16bf16_1k(a, b, c, 0, 0, 0);
}
#elif __has_builtin(__builtin_amdgcn_mfma_f32_16x16x16_bf16)
__device__ __forceinline__ f32x4 mfma16(bf16x4 a, bf16x4 b, f32x4 c) {
    return __builtin_amdgcn_mfma_f32_16x16x16_bf16(a, b, c, 0, 0, 0);
}
#else
__device__ __forceinline__ f32x4 mfma16(bf16x4 a, bf16x4 b, f32x4 c) {
    asm volatile("v_mfma_f32_16x16x16_bf16 %0, %1, %2, %0\n\ts_nop 7\n\ts_nop 7"
                 : "+v"(c) : "v"(a), "v"(b));
    return c;
}
#endif

// fp32 -> bf16 round-to-nearest-even (returns low 16 bits)
__device__ __forceinline__ unsigned f2bf(float x) {
    unsigned u = __float_as_uint(x);
    return (u + 0x7FFFu + ((u >> 16) & 1u)) >> 16;
}

__device__ __forceinline__ void split2(float x, unsigned short& h, unsigned short& l) {
    unsigned hh = f2bf(x);
    h = (unsigned short)hh;
    l = (unsigned short)f2bf(x - __uint_as_float(hh << 16));
}

// ---------------------------------------------------------------------------
// RoPE cos/sin table: [S][32] each, double precision angles.
// ---------------------------------------------------------------------------
__global__ void rope_table(float* __restrict__ ct, float* __restrict__ st_) {
    int id = blockIdx.x * 256 + threadIdx.x;
    int s = id >> 5;
    int i = id & 31;
    double invf = pow(10000.0, -(double)i / 32.0);
    double ang = (double)s * invf;
    ct[id] = (float)cos(ang);
    st_[id] = (float)sin(ang);
}

// ---------------------------------------------------------------------------
// Convert: x -> bf16 hi; Wq/Wk/Wv -> hi; Wo -> hi + lo.
// ---------------------------------------------------------------------------
__global__ void split_xw(const float* __restrict__ x,
                         const float* __restrict__ Wq, const float* __restrict__ Wk,
                         const float* __restrict__ Wv, const float* __restrict__ Wo,
                         unsigned short* __restrict__ xh,
                         unsigned short* __restrict__ whAll, unsigned short* __restrict__ wlAll) {
    int y = blockIdx.y;
    const float* src;
    unsigned short* h;
    unsigned short* l = nullptr;
    int n;
    if (y == 0) { src = x; h = xh; n = 1 << 22; }
    else {
        src = (y == 1) ? Wq : (y == 2) ? Wk : (y == 3) ? Wv : Wo;
        h = whAll + (size_t)(y - 1) * (1 << 20);
        if (y == 4) l = wlAll + (size_t)3 * (1 << 20);
        n = 1 << 20;
    }
    int i = (blockIdx.x * 256 + threadIdx.x) * 4;
    if (i >= n) return;
    float4 v = *(const float4*)(src + i);
    us4 hh;
    ((unsigned short*)&hh)[0] = (unsigned short)f2bf(v.x);
    ((unsigned short*)&hh)[1] = (unsigned short)f2bf(v.y);
    ((unsigned short*)&hh)[2] = (unsigned short)f2bf(v.z);
    ((unsigned short*)&hh)[3] = (unsigned short)f2bf(v.w);
    *(us4*)(h + i) = hh;
    if (l) {
        us4 ll;
        const float* vp = (const float*)&v;
#pragma unroll
        for (int e = 0; e < 4; e++) {
            unsigned short hi = ((unsigned short*)&hh)[e];
            ((unsigned short*)&ll)[e] =
                (unsigned short)f2bf(vp[e] - __uint_as_float((unsigned)hi << 16));
        }
        *(us4*)(l + i) = ll;
    }
}

// ---------------------------------------------------------------------------
// QKV GEMM, bf16 1-product, 128x128 tile, BK=32, dbuf. m-fastest grid.
// Epilogues: z=0 Q (RoPE+QSC row-major), z=1 K (RoPE, [T][kb][tok][8] cells),
//            z=2 V (V^T cells [T][tt*4+qk][d_swz][4], quad-swizzled, us4 packed)
// ---------------------------------------------------------------------------
__global__ __launch_bounds__(256) void gemm_qkv(
    const unsigned short* __restrict__ Ah,
    const unsigned short* __restrict__ whAll,
    unsigned short* __restrict__ Qh,
    unsigned short* __restrict__ Kh,
    unsigned short* __restrict__ Vh,
    const float* __restrict__ ct, const float* __restrict__ st_) {
    constexpr int K = 1024;
    __shared__ __align__(16) unsigned short AsH[2 * 4096], BsH[2 * 4096];

    const int z = blockIdx.z;
    const unsigned short* Wh = whAll + (size_t)z * (1 << 20);

    const int t = threadIdx.x;
    const int lane = t & 63;
    const int wave = t >> 6;
    const int l = lane & 15;
    const int quad = lane >> 4;
    const int wr = wave >> 1, wc = wave & 1;
    const int m0 = blockIdx.x * 128;
    const int n0 = blockIdx.y * 128;

    const int s_tensor = wave >> 1;
    const int s_rb = wave & 1;
    unsigned short* larr = s_tensor ? BsH : AsH;
    const unsigned short* gbase =
        (s_tensor ? Wh + (size_t)(n0 + s_rb * 64 + lane) * K
                  : Ah + (size_t)(m0 + s_rb * 64 + lane) * K);

    f32x4 acc[4][4];
#pragma unroll
    for (int i = 0; i < 4; i++)
#pragma unroll
        for (int j = 0; j < 4; j++) acc[i][j] = (f32x4){0.f, 0.f, 0.f, 0.f};

#pragma unroll
    for (int q = 0; q < 4; q++)
        __builtin_amdgcn_global_load_lds(
            (const __attribute__((address_space(1))) unsigned int*)(gbase + q * 8),
            (__attribute__((address_space(3))) unsigned int*)(larr + (q * 128 + s_rb * 64) * 8),
            16, 0, 0);

    for (int it = 0; it < 32; ++it) {
        __syncthreads();
        if (it + 1 < 32) {
            const unsigned short* g = gbase + (it + 1) * 32;
            unsigned short* buf = larr + ((it + 1) & 1) * 4096;
#pragma unroll
            for (int q = 0; q < 4; q++)
                __builtin_amdgcn_global_load_lds(
                    (const __attribute__((address_space(1))) unsigned int*)(g + q * 8),
                    (__attribute__((address_space(3))) unsigned int*)(buf + (q * 128 + s_rb * 64) * 8),
                    16, 0, 0);
        }
        const unsigned short* a = AsH + (it & 1) * 4096;
        const unsigned short* bb = BsH + (it & 1) * 4096;
        bf16x8 ah[4], bh[4];
#pragma unroll
        for (int i = 0; i < 4; i++) {
            ah[i] = *(const bf16x8*)&a[(quad * 128 + wr * 64 + i * 16 + l) * 8];
            bh[i] = *(const bf16x8*)&bb[(quad * 128 + wc * 64 + i * 16 + l) * 8];
        }
#pragma unroll
        for (int i = 0; i < 4; i++)
#pragma unroll
            for (int j = 0; j < 4; j++)
                acc[i][j] = __builtin_amdgcn_mfma_f32_16x16x32_bf16(ah[i], bh[j], acc[i][j], 0, 0, 0);
    }

    // ---- fused epilogue ----
    const int hcol = ((n0 + wc * 64) >> 6);   // head index 0..15
    if (z == 2) {
        // V^T cells: tile [tok-group i][qk=quad][d' = j*16 + (l^(quad*4))][r]
#pragma unroll
        for (int i = 0; i < 4; i++) {
            int m_base = m0 + wr * 64 + i * 16 + quad * 4;
            int bbk = m_base >> 11;
            int T = (m_base & (Sc - 1)) >> 6;
            size_t tilebase = (((size_t)(bbk * Hc + hcol)) * 32 + T) * 4096;
#pragma unroll
            for (int j = 0; j < 4; j++) {
                int dsw = j * 16 + (l ^ (quad << 2));
                size_t off = tilebase + (size_t)((i * 4 + quad) * 64 + dsw) * 4;
                us4 v4;
#pragma unroll
                for (int r = 0; r < 4; r++)
                    ((unsigned short*)&v4)[r] = (unsigned short)f2bf(acc[i][j][r]);
                *(us4*)(Vh + off) = v4;
            }
        }
    } else {
#pragma unroll
        for (int i = 0; i < 4; i++)
#pragma unroll
            for (int r = 0; r < 4; r++) {
                int m = m0 + wr * 64 + i * 16 + quad * 4 + r;
                int bbk = m >> 11, s = m & (Sc - 1);
#pragma unroll
                for (int jp = 0; jp < 2; jp++) {
                    int d = jp * 16 + l;                       // 0..31
                    float cs = ct[s * 32 + d];
                    float sn = st_[s * 32 + d];
                    float x0 = acc[i][jp][r];
                    float x1 = acc[i][jp + 2][r];
                    float y0 = x0 * cs - x1 * sn;
                    float y1 = x1 * cs + x0 * sn;
                    if (z == 0) {
                        size_t rowb = (((size_t)(bbk * Hc + hcol)) * Sc + s) * HDc;
                        Qh[rowb + d]      = (unsigned short)f2bf(y0 * QSC);
                        Qh[rowb + d + 32] = (unsigned short)f2bf(y1 * QSC);
                    } else {
                        int T = s >> 6, tok = s & 63;
                        size_t tb = (((size_t)(bbk * Hc + hcol)) * 32 + T) * 8;
                        size_t off0 = ((tb + (d >> 3)) * 64 + tok) * 8 + (d & 7);
                        size_t off1 = ((tb + (d >> 3) + 4) * 64 + tok) * 8 + (d & 7);
                        Kh[off0] = (unsigned short)f2bf(y0);
                        Kh[off1] = (unsigned short)f2bf(y1);
                    }
                }
            }
    }
}

// ---------------------------------------------------------------------------
// MFMA flash attention v6 (transposed): S^T = K @ Q^T; P^T stays in registers
// (C-frag == K=16 B-frag layout); O^T = V^T @ P^T via 16x16x16; l via ONES-A.
// No P LDS round-trip, no rescale, dbuf DMA staging.
// ---------------------------------------------------------------------------
__global__ __launch_bounds__(256) void attn6(
    const unsigned short* __restrict__ Qh,
    const unsigned short* __restrict__ Kh,
    const unsigned short* __restrict__ Vh,
    unsigned short* __restrict__ AOh, unsigned short* __restrict__ AOl) {
    __shared__ __align__(16) unsigned short KsH[2 * 4096], VtH[2 * 4096];

    const int t = threadIdx.x;
    const int lane = t & 63;
    const int wave = t >> 6;
    const int l = lane & 15;
    const int quad = lane >> 4;
    const int id = blockIdx.x;                 // 0..511
    const int bh = (id & 7) * 4 + (id >> 7);   // XCD-clustered
    const int qt = (id >> 3) & 15;
    const int q0 = qt * 128;
    const int b = bh >> 4;
    const int hh = bh & 15;

    const bf16x4 ONES4 = {(short)0x3F80, (short)0x3F80, (short)0x3F80, (short)0x3F80};

    // Q fragments (B operand: n=q=lane&15, k=d=quad*8+j)
    bf16x8 qf[2][2];
#pragma unroll
    for (int bnd = 0; bnd < 2; bnd++) {
        size_t rowb = ((size_t)bh * Sc + q0 + bnd * 64 + wave * 16 + l) * HDc;
#pragma unroll
        for (int ks = 0; ks < 2; ks++)
            qf[bnd][ks] = *(const bf16x8*)(Qh + rowb + ks * 32 + quad * 8);
    }

    f32x4 o[2][4], lac[2];
#pragma unroll
    for (int bnd = 0; bnd < 2; bnd++) {
        lac[bnd] = (f32x4){0.f, 0.f, 0.f, 0.f};
#pragma unroll
        for (int i = 0; i < 4; i++) o[bnd][i] = (f32x4){0.f, 0.f, 0.f, 0.f};
    }

    const int s_tensor = wave >> 1;
    const int s_cg = wave & 1;
    unsigned short* larr = s_tensor ? VtH : KsH;
    const unsigned short* gB =
        (s_tensor ? Vh : Kh) + (size_t)bh * Sc * HDc + (s_cg * 4) * 512 + lane * 8;

#pragma unroll
    for (int q = 0; q < 4; q++)
        __builtin_amdgcn_global_load_lds(
            (const __attribute__((address_space(1))) unsigned int*)(gB + q * 512),
            (__attribute__((address_space(3))) unsigned int*)(larr + (s_cg * 4 + q) * 512),
            16, 0, 0);

    for (int kt = 0; kt < 32; kt++) {
        __syncthreads();
        if (kt + 1 < 32) {
            const unsigned short* g = gB + (size_t)(kt + 1) * 4096;
            unsigned short* buf = larr + ((kt + 1) & 1) * 4096;
#pragma unroll
            for (int q = 0; q < 4; q++)
                __builtin_amdgcn_global_load_lds(
                    (const __attribute__((address_space(1))) unsigned int*)(g + q * 512),
                    (__attribute__((address_space(3))) unsigned int*)(buf + (s_cg * 4 + q) * 512),
                    16, 0, 0);
        }
        const unsigned short* Kbuf = KsH + (kt & 1) * 4096;
        const unsigned short* Vbuf = VtH + (kt & 1) * 4096;

        // ---- S^T = K @ Q^T: A=K frag (m=tok), B=Q frag (n=q) ----
        f32x4 s[2][4];
#pragma unroll
        for (int bnd = 0; bnd < 2; bnd++)
#pragma unroll
            for (int tt = 0; tt < 4; tt++) s[bnd][tt] = (f32x4){0.f, 0.f, 0.f, 0.f};
#pragma unroll
        for (int ks = 0; ks < 2; ks++)
#pragma unroll
            for (int tt = 0; tt < 4; tt++) {
                bf16x8 kf = *(const bf16x8*)&Kbuf[((ks * 4 + quad) * 64 + tt * 16 + l) * 8];
                s[0][tt] = __builtin_amdgcn_mfma_f32_16x16x32_bf16(kf, qf[0][ks], s[0][tt], 0, 0, 0);
                s[1][tt] = __builtin_amdgcn_mfma_f32_16x16x32_bf16(kf, qf[1][ks], s[1][tt], 0, 0, 0);
            }

        // ---- P^T = exp2(S^T) trunc-bf16, packed in-register as K=16 B-frags ----
        bf16x4 pt[2][4];
#pragma unroll
        for (int bnd = 0; bnd < 2; bnd++)
#pragma unroll
            for (int tt = 0; tt < 4; tt++) {
                unsigned u0 = __float_as_uint(exp2f(s[bnd][tt][0]));
                unsigned u1 = __float_as_uint(exp2f(s[bnd][tt][1]));
                unsigned u2 = __float_as_uint(exp2f(s[bnd][tt][2]));
                unsigned u3 = __float_as_uint(exp2f(s[bnd][tt][3]));
                u32x2 pr = {(u0 >> 16) | (u1 & 0xFFFF0000u),
                            (u2 >> 16) | (u3 & 0xFFFF0000u)};
                pt[bnd][tt] = __builtin_bit_cast(bf16x4, pr);
                lac[bnd] = mfma16(ONES4, pt[bnd][tt], lac[bnd]);
            }

        // ---- O^T += V^T @ P^T (V frags shared across bands) ----
#pragma unroll
        for (int dd = 0; dd < 4; dd++)
#pragma unroll
            for (int tt = 0; tt < 4; tt++) {
                bf16x4 vf = *(const bf16x4*)
                    &Vbuf[(size_t)((tt * 4 + quad) * 64 + dd * 16 + (l ^ (quad << 2))) * 4];
                o[0][dd] = mfma16(vf, pt[0][tt], o[0][dd]);
                o[1][dd] = mfma16(vf, pt[1][tt], o[1][dd]);
            }
    }

    // ---- epilogue: O^T frag: col q = lane&15, row d = dd*16 + quad*4 + r ----
#pragma unroll
    for (int bnd = 0; bnd < 2; bnd++) {
        float inv = 1.f / lac[bnd][0];   // all 4 regs equal (ONES-A rows identical)
        int q = q0 + bnd * 64 + wave * 16 + l;
        size_t rowb = ((size_t)b * Sc + q) * Dc + hh * HDc + quad * 4;
#pragma unroll
        for (int dd = 0; dd < 4; dd++) {
            us4 h4, l4;
#pragma unroll
            for (int r = 0; r < 4; r++)
                split2(o[bnd][dd][r] * inv,
                       ((unsigned short*)&h4)[r], ((unsigned short*)&l4)[r]);
            *(us4*)(AOh + rowb + dd * 16) = h4;
            *(us4*)(AOl + rowb + dd * 16) = l4;
        }
    }
}

// ---------------------------------------------------------------------------
// Output projection GEMM (split-bf16 3-product, dbuf), 128x64 tile -> 2 blk/CU.
// ---------------------------------------------------------------------------
__global__ __launch_bounds__(256) void gemm_out(
    const unsigned short* __restrict__ Ah, const unsigned short* __restrict__ Al,
    const unsigned short* __restrict__ Wh, const unsigned short* __restrict__ Wl,
    float* __restrict__ C) {
    constexpr int K = 1024;
    __shared__ __align__(16) unsigned short AsH[2 * 4096], AsL[2 * 4096],
                                            BsH[2 * 2048], BsL[2 * 2048];

    const int t = threadIdx.x;
    const int lane = t & 63;
    const int wave = t >> 6;
    const int l = lane & 15;
    const int quad = lane >> 4;
    const int wr = wave >> 1, wc = wave & 1;
    const int m0 = blockIdx.x * 128;   // m fastest -> XCD A-locality
    const int n0 = blockIdx.y * 64;

    // staging: wave0 A-hi (8 jobs), wave1 A-lo (8), wave2 B-hi (4), wave3 B-lo (4)
    unsigned short* larr = (wave == 0) ? AsH : (wave == 1) ? AsL : (wave == 2) ? BsH : BsL;
    const unsigned short* garr = (wave == 0) ? Ah : (wave == 1) ? Al : (wave == 2) ? Wh : Wl;
    const int njobs = (wave < 2) ? 8 : 4;
    const int bufsz = (wave < 2) ? 4096 : 2048;

    const unsigned short* gsrc[8];
    int ldst[8];
#pragma unroll
    for (int q = 0; q < 8; q++) {
        if (wave < 2) {
            int rb = q >> 2, kb = q & 3;
            gsrc[q] = garr + (size_t)(m0 + rb * 64 + lane) * K + kb * 8;
            ldst[q] = (kb * 128 + rb * 64) * 8;
        } else {
            int kb = q & 3;
            gsrc[q] = garr + (size_t)(n0 + lane) * K + kb * 8;
            ldst[q] = (kb * 64) * 8;
        }
    }

    f32x4 acc[4][2];
#pragma unroll
    for (int i = 0; i < 4; i++)
#pragma unroll
        for (int j = 0; j < 2; j++) acc[i][j] = (f32x4){0.f, 0.f, 0.f, 0.f};

    for (int q = 0; q < njobs; q++)
        __builtin_amdgcn_global_load_lds(
            (const __attribute__((address_space(1))) unsigned int*)gsrc[q],
            (__attribute__((address_space(3))) unsigned int*)(larr + ldst[q]), 16, 0, 0);

    for (int it = 0; it < 32; ++it) {
        __syncthreads();
        if (it + 1 < 32) {
            unsigned short* buf = larr + ((it + 1) & 1) * bufsz;
            int koff = (it + 1) * 32;
            for (int q = 0; q < njobs; q++)
                __builtin_amdgcn_global_load_lds(
                    (const __attribute__((address_space(1))) unsigned int*)(gsrc[q] + koff),
                    (__attribute__((address_space(3))) unsigned int*)(buf + ldst[q]), 16, 0, 0);
        }
        const int ao = (it & 1) * 4096;
        const int bo = (it & 1) * 2048;
        bf16x8 ah[4], al[4], bh[2], bl[2];
#pragma unroll
        for (int i = 0; i < 4; i++) {
            int ra = ao + (quad * 128 + wr * 64 + i * 16 + l) * 8;
            ah[i] = *(const bf16x8*)&AsH[ra];
            al[i] = *(const bf16x8*)&AsL[ra];
        }
#pragma unroll
        for (int j = 0; j < 2; j++) {
            int rb2 = bo + (quad * 64 + wc * 32 + j * 16 + l) * 8;
            bh[j] = *(const bf16x8*)&BsH[rb2];
            bl[j] = *(const bf16x8*)&BsL[rb2];
        }
#pragma unroll
        for (int i = 0; i < 4; i++)
#pragma unroll
            for (int j = 0; j < 2; j++) {
                acc[i][j] = __builtin_amdgcn_mfma_f32_16x16x32_bf16(ah[i], bh[j], acc[i][j], 0, 0, 0);
                acc[i][j] = __builtin_amdgcn_mfma_f32_16x16x32_bf16(al[i], bh[j], acc[i][j], 0, 0, 0);
                acc[i][j] = __builtin_amdgcn_mfma_f32_16x16x32_bf16(ah[i], bl[j], acc[i][j], 0, 0, 0);
            }
    }

#pragma unroll
    for (int i = 0; i < 4; i++)
#pragma unroll
        for (int j = 0; j < 2; j++)
#pragma unroll
            for (int r = 0; r < 4; r++) {
                int m = m0 + wr * 64 + i * 16 + quad * 4 + r;
                int n = n0 + wc * 32 + j * 16 + l;
                C[(size_t)m * Dc + n] = acc[i][j][r];
            }
}

// ---------------------------------------------------------------------------
extern "C" void kernel_launch(void* const* d_in, const int* in_sizes, int n_in,
                              void* d_out, int out_size, void* d_ws, size_t ws_size,
                              hipStream_t stream) {
    const float* x  = (const float*)d_in[0];
    const float* Wq = (const float*)d_in[1];
    const float* Wk = (const float*)d_in[2];
    const float* Wv = (const float*)d_in[3];
    const float* Wo = (const float*)d_in[4];
    float* out = (float*)d_out;

    unsigned short* usw = (unsigned short*)d_ws;
    const size_t M4 = (size_t)1 << 22;   // 4M elements
    unsigned short* whAll = usw;                 // 4 x 1M weights hi
    unsigned short* wlAll = usw + M4;            // lo (only Wo slot used)
    unsigned short* xh = usw + 2 * M4;           // x hi (later AOh)
    unsigned short* xl = usw + 3 * M4;           // later AOl
    unsigned short* Qh = usw + 4 * M4;
    unsigned short* Kh = usw + 5 * M4;
    unsigned short* Vh = usw + 6 * M4;
    float* ct = (float*)(usw + 7 * M4);
    float* st_ = ct + (size_t)Sc * 32;
    unsigned short* AOh = xh;   // x dead after QKV GEMM
    unsigned short* AOl = xl;

    // 1. RoPE table
    rope_table<<<dim3((Sc * 32) / 256), dim3(256), 0, stream>>>(ct, st_);
    // 2. convert x + weights to bf16 (Wo keeps hi/lo)
    split_xw<<<dim3(4096, 5), dim3(256), 0, stream>>>(x, Wq, Wk, Wv, Wo, xh, whAll, wlAll);
    // 3. QKV projections (1-product bf16, dbuf) with fused epilogues
    gemm_qkv<<<dim3(32, 8, 3), dim3(256), 0, stream>>>(
        xh, whAll, Qh, Kh, Vh, ct, st_);
    // 4. attention (transposed, register-resident P) -> AOh/AOl
    attn6<<<dim3(512), dim3(256), 0, stream>>>(Qh, Kh, Vh, AOh, AOl);
    // 5. output projection (3-product, 128x64 tiles, 2 blk/CU)
    gemm_out<<<dim3(32, 16), dim3(256), 0, stream>>>(
        AOh, AOl, whAll + 3 * (1 << 20), wlAll + 3 * (1 << 20), out);
}

// Round 9
// 251.810 us; speedup vs baseline: 1.1388x; 1.1388x over previous
//
#include <hip/hip_runtime.h>
#include <math.h>

// Problem constants
constexpr int Bc = 2;
constexpr int Sc = 2048;
constexpr int Dc = 1024;
constexpr int Hc = 16;
constexpr int HDc = 64;

// Q pre-scale: attention 1/sqrt(64) folded with log2(e) for exp2-domain softmax
constexpr float QSC = 0.125f * 1.4426950408889634f;

typedef __attribute__((ext_vector_type(8))) short bf16x8;
typedef __attribute__((ext_vector_type(4))) short bf16x4;
typedef __attribute__((ext_vector_type(4))) float f32x4;
typedef __attribute__((ext_vector_type(4))) unsigned short us4;
typedef __attribute__((ext_vector_type(2))) unsigned int u32x2;

// K=16 bf16 MFMA (A/B = 4 bf16): builtin name varies; hedge + asm fallback.
#if __has_builtin(__builtin_amdgcn_mfma_f32_16x16x16bf16_1k)
__device__ __forceinline__ f32x4 mfma16(bf16x4 a, bf16x4 b, f32x4 c) {
    return __builtin_amdgcn_mfma_f32_16x16x16bf16_1k(a, b, c, 0, 0, 0);
}
#elif __has_builtin(__builtin_amdgcn_mfma_f32_16x16x16_bf16)
__device__ __forceinline__ f32x4 mfma16(bf16x4 a, bf16x4 b, f32x4 c) {
    return __builtin_amdgcn_mfma_f32_16x16x16_bf16(a, b, c, 0, 0, 0);
}
#else
__device__ __forceinline__ f32x4 mfma16(bf16x4 a, bf16x4 b, f32x4 c) {
    asm volatile("v_mfma_f32_16x16x16_bf16 %0, %1, %2, %0\n\ts_nop 7\n\ts_nop 7"
                 : "+v"(c) : "v"(a), "v"(b));
    return c;
}
#endif

// fp32 -> bf16 round-to-nearest-even (returns low 16 bits)
__device__ __forceinline__ unsigned f2bf(float x) {
    unsigned u = __float_as_uint(x);
    return (u + 0x7FFFu + ((u >> 16) & 1u)) >> 16;
}

__device__ __forceinline__ void split2(float x, unsigned short& h, unsigned short& l) {
    unsigned hh = f2bf(x);
    h = (unsigned short)hh;
    l = (unsigned short)f2bf(x - __uint_as_float(hh << 16));
}

// ---------------------------------------------------------------------------
// RoPE cos/sin table: [S][32] each, double precision angles.
// ---------------------------------------------------------------------------
__global__ void rope_table(float* __restrict__ ct, float* __restrict__ st_) {
    int id = blockIdx.x * 256 + threadIdx.x;
    int s = id >> 5;
    int i = id & 31;
    double invf = pow(10000.0, -(double)i / 32.0);
    double ang = (double)s * invf;
    ct[id] = (float)cos(ang);
    st_[id] = (float)sin(ang);
}

// ---------------------------------------------------------------------------
// Convert: x -> bf16 hi; Wq/Wk/Wv -> hi; Wo -> hi + lo.
// ---------------------------------------------------------------------------
__global__ void split_xw(const float* __restrict__ x,
                         const float* __restrict__ Wq, const float* __restrict__ Wk,
                         const float* __restrict__ Wv, const float* __restrict__ Wo,
                         unsigned short* __restrict__ xh,
                         unsigned short* __restrict__ whAll, unsigned short* __restrict__ wlAll) {
    int y = blockIdx.y;
    const float* src;
    unsigned short* h;
    unsigned short* l = nullptr;
    int n;
    if (y == 0) { src = x; h = xh; n = 1 << 22; }
    else {
        src = (y == 1) ? Wq : (y == 2) ? Wk : (y == 3) ? Wv : Wo;
        h = whAll + (size_t)(y - 1) * (1 << 20);
        if (y == 4) l = wlAll + (size_t)3 * (1 << 20);
        n = 1 << 20;
    }
    int i = (blockIdx.x * 256 + threadIdx.x) * 4;
    if (i >= n) return;
    float4 v = *(const float4*)(src + i);
    us4 hh;
    ((unsigned short*)&hh)[0] = (unsigned short)f2bf(v.x);
    ((unsigned short*)&hh)[1] = (unsigned short)f2bf(v.y);
    ((unsigned short*)&hh)[2] = (unsigned short)f2bf(v.z);
    ((unsigned short*)&hh)[3] = (unsigned short)f2bf(v.w);
    *(us4*)(h + i) = hh;
    if (l) {
        us4 ll;
        const float* vp = (const float*)&v;
#pragma unroll
        for (int e = 0; e < 4; e++) {
            unsigned short hi = ((unsigned short*)&hh)[e];
            ((unsigned short*)&ll)[e] =
                (unsigned short)f2bf(vp[e] - __uint_as_float((unsigned)hi << 16));
        }
        *(us4*)(l + i) = ll;
    }
}

// ---------------------------------------------------------------------------
// QKV GEMM, bf16 1-product, 128x128 tile, BK=32, dbuf. m-fastest grid.
// Epilogues: z=0 Q (RoPE+QSC row-major), z=1 K (RoPE, [T][kb][tok][8] cells),
//            z=2 V (V^T cells [T][tt*4+qk][d_swz][4], quad-swizzled, us4 packed)
// ---------------------------------------------------------------------------
__global__ __launch_bounds__(256) void gemm_qkv(
    const unsigned short* __restrict__ Ah,
    const unsigned short* __restrict__ whAll,
    unsigned short* __restrict__ Qh,
    unsigned short* __restrict__ Kh,
    unsigned short* __restrict__ Vh,
    const float* __restrict__ ct, const float* __restrict__ st_) {
    constexpr int K = 1024;
    __shared__ __align__(16) unsigned short AsH[2 * 4096], BsH[2 * 4096];

    const int z = blockIdx.z;
    const unsigned short* Wh = whAll + (size_t)z * (1 << 20);

    const int t = threadIdx.x;
    const int lane = t & 63;
    const int wave = t >> 6;
    const int l = lane & 15;
    const int quad = lane >> 4;
    const int wr = wave >> 1, wc = wave & 1;
    const int m0 = blockIdx.x * 128;
    const int n0 = blockIdx.y * 128;

    const int s_tensor = wave >> 1;
    const int s_rb = wave & 1;
    unsigned short* larr = s_tensor ? BsH : AsH;
    const unsigned short* gbase =
        (s_tensor ? Wh + (size_t)(n0 + s_rb * 64 + lane) * K
                  : Ah + (size_t)(m0 + s_rb * 64 + lane) * K);

    f32x4 acc[4][4];
#pragma unroll
    for (int i = 0; i < 4; i++)
#pragma unroll
        for (int j = 0; j < 4; j++) acc[i][j] = (f32x4){0.f, 0.f, 0.f, 0.f};

#pragma unroll
    for (int q = 0; q < 4; q++)
        __builtin_amdgcn_global_load_lds(
            (const __attribute__((address_space(1))) unsigned int*)(gbase + q * 8),
            (__attribute__((address_space(3))) unsigned int*)(larr + (q * 128 + s_rb * 64) * 8),
            16, 0, 0);

    for (int it = 0; it < 32; ++it) {
        __syncthreads();
        if (it + 1 < 32) {
            const unsigned short* g = gbase + (it + 1) * 32;
            unsigned short* buf = larr + ((it + 1) & 1) * 4096;
#pragma unroll
            for (int q = 0; q < 4; q++)
                __builtin_amdgcn_global_load_lds(
                    (const __attribute__((address_space(1))) unsigned int*)(g + q * 8),
                    (__attribute__((address_space(3))) unsigned int*)(buf + (q * 128 + s_rb * 64) * 8),
                    16, 0, 0);
        }
        const unsigned short* a = AsH + (it & 1) * 4096;
        const unsigned short* bb = BsH + (it & 1) * 4096;
        bf16x8 ah[4], bh[4];
#pragma unroll
        for (int i = 0; i < 4; i++) {
            ah[i] = *(const bf16x8*)&a[(quad * 128 + wr * 64 + i * 16 + l) * 8];
            bh[i] = *(const bf16x8*)&bb[(quad * 128 + wc * 64 + i * 16 + l) * 8];
        }
#pragma unroll
        for (int i = 0; i < 4; i++)
#pragma unroll
            for (int j = 0; j < 4; j++)
                acc[i][j] = __builtin_amdgcn_mfma_f32_16x16x32_bf16(ah[i], bh[j], acc[i][j], 0, 0, 0);
    }

    // ---- fused epilogue ----
    const int hcol = ((n0 + wc * 64) >> 6);   // head index 0..15
    if (z == 2) {
        // V^T cells: tile [tok-group i][qk=quad][d' = j*16 + (l^(quad*4))][r]
#pragma unroll
        for (int i = 0; i < 4; i++) {
            int m_base = m0 + wr * 64 + i * 16 + quad * 4;
            int bbk = m_base >> 11;
            int T = (m_base & (Sc - 1)) >> 6;
            size_t tilebase = (((size_t)(bbk * Hc + hcol)) * 32 + T) * 4096;
#pragma unroll
            for (int j = 0; j < 4; j++) {
                int dsw = j * 16 + (l ^ (quad << 2));
                size_t off = tilebase + (size_t)((i * 4 + quad) * 64 + dsw) * 4;
                us4 v4;
#pragma unroll
                for (int r = 0; r < 4; r++)
                    ((unsigned short*)&v4)[r] = (unsigned short)f2bf(acc[i][j][r]);
                *(us4*)(Vh + off) = v4;
            }
        }
    } else {
#pragma unroll
        for (int i = 0; i < 4; i++)
#pragma unroll
            for (int r = 0; r < 4; r++) {
                int m = m0 + wr * 64 + i * 16 + quad * 4 + r;
                int bbk = m >> 11, s = m & (Sc - 1);
#pragma unroll
                for (int jp = 0; jp < 2; jp++) {
                    int d = jp * 16 + l;                       // 0..31
                    float cs = ct[s * 32 + d];
                    float sn = st_[s * 32 + d];
                    float x0 = acc[i][jp][r];
                    float x1 = acc[i][jp + 2][r];
                    float y0 = x0 * cs - x1 * sn;
                    float y1 = x1 * cs + x0 * sn;
                    if (z == 0) {
                        size_t rowb = (((size_t)(bbk * Hc + hcol)) * Sc + s) * HDc;
                        Qh[rowb + d]      = (unsigned short)f2bf(y0 * QSC);
                        Qh[rowb + d + 32] = (unsigned short)f2bf(y1 * QSC);
                    } else {
                        int T = s >> 6, tok = s & 63;
                        size_t tb = (((size_t)(bbk * Hc + hcol)) * 32 + T) * 8;
                        size_t off0 = ((tb + (d >> 3)) * 64 + tok) * 8 + (d & 7);
                        size_t off1 = ((tb + (d >> 3) + 4) * 64 + tok) * 8 + (d & 7);
                        Kh[off0] = (unsigned short)f2bf(y0);
                        Kh[off1] = (unsigned short)f2bf(y1);
                    }
                }
            }
    }
}

// ---------------------------------------------------------------------------
// MFMA flash attention v7 (transposed, register-resident P):
// 64 q/block, 2 waves x 2 bands -> grid 1024 = 4 blocks/CU (decorrelated
// barriers; one block's DMA drain overlaps 3 others' compute).
// exp2 via raw v_exp_f32 builtin; P packing via v_perm.
// ---------------------------------------------------------------------------
__global__ __launch_bounds__(128) void attn7(
    const unsigned short* __restrict__ Qh,
    const unsigned short* __restrict__ Kh,
    const unsigned short* __restrict__ Vh,
    unsigned short* __restrict__ AOh, unsigned short* __restrict__ AOl) {
    __shared__ __align__(16) unsigned short KsH[2 * 4096], VtH[2 * 4096];

    const int t = threadIdx.x;
    const int lane = t & 63;
    const int wave = t >> 6;               // 0..1
    const int l = lane & 15;
    const int quad = lane >> 4;
    const int id = blockIdx.x;             // 0..1023
    const int bh = (id & 7) * 4 + (id >> 8);   // XCD-clustered (4 bh / XCD)
    const int qt = (id >> 3) & 31;
    const int q0 = qt * 64;
    const int b = bh >> 4;
    const int hh = bh & 15;

    const bf16x4 ONES4 = {(short)0x3F80, (short)0x3F80, (short)0x3F80, (short)0x3F80};

    // Q fragments (B operand: n=q=lane&15, k=d=quad*8+j); band bnd -> rows
    // q0 + bnd*32 + wave*16 + l
    bf16x8 qf[2][2];
#pragma unroll
    for (int bnd = 0; bnd < 2; bnd++) {
        size_t rowb = ((size_t)bh * Sc + q0 + bnd * 32 + wave * 16 + l) * HDc;
#pragma unroll
        for (int ks = 0; ks < 2; ks++)
            qf[bnd][ks] = *(const bf16x8*)(Qh + rowb + ks * 32 + quad * 8);
    }

    f32x4 o[2][4], lac[2];
#pragma unroll
    for (int bnd = 0; bnd < 2; bnd++) {
        lac[bnd] = (f32x4){0.f, 0.f, 0.f, 0.f};
#pragma unroll
        for (int i = 0; i < 4; i++) o[bnd][i] = (f32x4){0.f, 0.f, 0.f, 0.f};
    }

    // staging: wave 0 -> K, wave 1 -> V; 8 chunks of 512 elems each.
    unsigned short* larr = wave ? VtH : KsH;
    const unsigned short* gB = (wave ? Vh : Kh) + (size_t)bh * Sc * HDc + lane * 8;

#pragma unroll
    for (int q = 0; q < 8; q++)
        __builtin_amdgcn_global_load_lds(
            (const __attribute__((address_space(1))) unsigned int*)(gB + q * 512),
            (__attribute__((address_space(3))) unsigned int*)(larr + q * 512),
            16, 0, 0);

    for (int kt = 0; kt < 32; kt++) {
        __syncthreads();
        if (kt + 1 < 32) {
            const unsigned short* g = gB + (size_t)(kt + 1) * 4096;
            unsigned short* buf = larr + ((kt + 1) & 1) * 4096;
#pragma unroll
            for (int q = 0; q < 8; q++)
                __builtin_amdgcn_global_load_lds(
                    (const __attribute__((address_space(1))) unsigned int*)(g + q * 512),
                    (__attribute__((address_space(3))) unsigned int*)(buf + q * 512),
                    16, 0, 0);
        }
        const unsigned short* Kbuf = KsH + (kt & 1) * 4096;
        const unsigned short* Vbuf = VtH + (kt & 1) * 4096;

        // ---- S^T = K @ Q^T: A=K frag (m=tok), B=Q frag (n=q) ----
        f32x4 s[2][4];
#pragma unroll
        for (int bnd = 0; bnd < 2; bnd++)
#pragma unroll
            for (int tt = 0; tt < 4; tt++) s[bnd][tt] = (f32x4){0.f, 0.f, 0.f, 0.f};
#pragma unroll
        for (int ks = 0; ks < 2; ks++)
#pragma unroll
            for (int tt = 0; tt < 4; tt++) {
                bf16x8 kf = *(const bf16x8*)&Kbuf[((ks * 4 + quad) * 64 + tt * 16 + l) * 8];
                s[0][tt] = __builtin_amdgcn_mfma_f32_16x16x32_bf16(kf, qf[0][ks], s[0][tt], 0, 0, 0);
                s[1][tt] = __builtin_amdgcn_mfma_f32_16x16x32_bf16(kf, qf[1][ks], s[1][tt], 0, 0, 0);
            }

        // ---- P^T = exp2(S^T) trunc-bf16, packed in-register (v_perm) ----
        bf16x4 pt[2][4];
#pragma unroll
        for (int bnd = 0; bnd < 2; bnd++)
#pragma unroll
            for (int tt = 0; tt < 4; tt++) {
                unsigned u0 = __float_as_uint(__builtin_amdgcn_exp2f(s[bnd][tt][0]));
                unsigned u1 = __float_as_uint(__builtin_amdgcn_exp2f(s[bnd][tt][1]));
                unsigned u2 = __float_as_uint(__builtin_amdgcn_exp2f(s[bnd][tt][2]));
                unsigned u3 = __float_as_uint(__builtin_amdgcn_exp2f(s[bnd][tt][3]));
                u32x2 pr = {__builtin_amdgcn_perm(u1, u0, 0x07060302u),
                            __builtin_amdgcn_perm(u3, u2, 0x07060302u)};
                pt[bnd][tt] = __builtin_bit_cast(bf16x4, pr);
                lac[bnd] = mfma16(ONES4, pt[bnd][tt], lac[bnd]);
            }

        // ---- O^T += V^T @ P^T (V frags shared across bands) ----
#pragma unroll
        for (int dd = 0; dd < 4; dd++)
#pragma unroll
            for (int tt = 0; tt < 4; tt++) {
                bf16x4 vf = *(const bf16x4*)
                    &Vbuf[(size_t)((tt * 4 + quad) * 64 + dd * 16 + (l ^ (quad << 2))) * 4];
                o[0][dd] = mfma16(vf, pt[0][tt], o[0][dd]);
                o[1][dd] = mfma16(vf, pt[1][tt], o[1][dd]);
            }
    }

    // ---- epilogue: O^T frag: col q = lane&15, row d = dd*16 + quad*4 + r ----
#pragma unroll
    for (int bnd = 0; bnd < 2; bnd++) {
        float inv = 1.f / lac[bnd][0];   // all 4 regs equal (ONES-A rows identical)
        int q = q0 + bnd * 32 + wave * 16 + l;
        size_t rowb = ((size_t)b * Sc + q) * Dc + hh * HDc + quad * 4;
#pragma unroll
        for (int dd = 0; dd < 4; dd++) {
            us4 h4, l4;
#pragma unroll
            for (int r = 0; r < 4; r++)
                split2(o[bnd][dd][r] * inv,
                       ((unsigned short*)&h4)[r], ((unsigned short*)&l4)[r]);
            *(us4*)(AOh + rowb + dd * 16) = h4;
            *(us4*)(AOl + rowb + dd * 16) = l4;
        }
    }
}

// ---------------------------------------------------------------------------
// Output projection GEMM (MFMA split-bf16 3-product, dbuf), 128x128, fp32 out.
// ---------------------------------------------------------------------------
__global__ __launch_bounds__(256) void gemm_out(
    const unsigned short* __restrict__ Ah, const unsigned short* __restrict__ Al,
    const unsigned short* __restrict__ Wh, const unsigned short* __restrict__ Wl,
    float* __restrict__ C) {
    constexpr int K = 1024;
    __shared__ __align__(16) unsigned short AsH[2 * 4096], AsL[2 * 4096],
                                            BsH[2 * 4096], BsL[2 * 4096];

    const int t = threadIdx.x;
    const int lane = t & 63;
    const int wave = t >> 6;
    const int l = lane & 15;
    const int quad = lane >> 4;
    const int wr = wave >> 1, wc = wave & 1;
    const int m0 = blockIdx.x * 128;   // m fastest -> XCD A-locality
    const int n0 = blockIdx.y * 128;

    // staging: wave 0 = A-hi, 1 = A-lo, 2 = B-hi, 3 = B-lo; 8 jobs each.
    unsigned short* larr = (wave == 0) ? AsH : (wave == 1) ? AsL : (wave == 2) ? BsH : BsL;
    const unsigned short* garr = (wave == 0) ? Ah : (wave == 1) ? Al : (wave == 2) ? Wh : Wl;
    const int t0 = (wave < 2) ? m0 : n0;

    const unsigned short* gsrc[8];
    int ldst[8];
#pragma unroll
    for (int q = 0; q < 8; q++) {
        int rb = q >> 2;
        int kb = q & 3;
        gsrc[q] = garr + (size_t)(t0 + rb * 64 + lane) * K + kb * 8;
        ldst[q] = (kb * 128 + rb * 64) * 8;
    }

    f32x4 acc[4][4];
#pragma unroll
    for (int i = 0; i < 4; i++)
#pragma unroll
        for (int j = 0; j < 4; j++) acc[i][j] = (f32x4){0.f, 0.f, 0.f, 0.f};

#pragma unroll
    for (int q = 0; q < 8; q++)
        __builtin_amdgcn_global_load_lds(
            (const __attribute__((address_space(1))) unsigned int*)gsrc[q],
            (__attribute__((address_space(3))) unsigned int*)(larr + ldst[q]), 16, 0, 0);

    for (int it = 0; it < 32; ++it) {
        __syncthreads();
        if (it + 1 < 32) {
            unsigned short* buf = larr + ((it + 1) & 1) * 4096;
            int koff = (it + 1) * 32;
#pragma unroll
            for (int q = 0; q < 8; q++)
                __builtin_amdgcn_global_load_lds(
                    (const __attribute__((address_space(1))) unsigned int*)(gsrc[q] + koff),
                    (__attribute__((address_space(3))) unsigned int*)(buf + ldst[q]), 16, 0, 0);
        }
        const int bo = (it & 1) * 4096;
        bf16x8 ah[4], al[4], bh[4], bl[4];
#pragma unroll
        for (int i = 0; i < 4; i++) {
            int ra = bo + (quad * 128 + wr * 64 + i * 16 + l) * 8;
            ah[i] = *(const bf16x8*)&AsH[ra];
            al[i] = *(const bf16x8*)&AsL[ra];
            int rb2 = bo + (quad * 128 + wc * 64 + i * 16 + l) * 8;
            bh[i] = *(const bf16x8*)&BsH[rb2];
            bl[i] = *(const bf16x8*)&BsL[rb2];
        }
#pragma unroll
        for (int i = 0; i < 4; i++)
#pragma unroll
            for (int j = 0; j < 4; j++) {
                acc[i][j] = __builtin_amdgcn_mfma_f32_16x16x32_bf16(ah[i], bh[j], acc[i][j], 0, 0, 0);
                acc[i][j] = __builtin_amdgcn_mfma_f32_16x16x32_bf16(al[i], bh[j], acc[i][j], 0, 0, 0);
                acc[i][j] = __builtin_amdgcn_mfma_f32_16x16x32_bf16(ah[i], bl[j], acc[i][j], 0, 0, 0);
            }
    }

#pragma unroll
    for (int i = 0; i < 4; i++)
#pragma unroll
        for (int j = 0; j < 4; j++)
#pragma unroll
            for (int r = 0; r < 4; r++) {
                int m = m0 + wr * 64 + i * 16 + quad * 4 + r;
                int n = n0 + wc * 64 + j * 16 + l;
                C[(size_t)m * Dc + n] = acc[i][j][r];
            }
}

// ---------------------------------------------------------------------------
extern "C" void kernel_launch(void* const* d_in, const int* in_sizes, int n_in,
                              void* d_out, int out_size, void* d_ws, size_t ws_size,
                              hipStream_t stream) {
    const float* x  = (const float*)d_in[0];
    const float* Wq = (const float*)d_in[1];
    const float* Wk = (const float*)d_in[2];
    const float* Wv = (const float*)d_in[3];
    const float* Wo = (const float*)d_in[4];
    float* out = (float*)d_out;

    unsigned short* usw = (unsigned short*)d_ws;
    const size_t M4 = (size_t)1 << 22;   // 4M elements
    unsigned short* whAll = usw;                 // 4 x 1M weights hi
    unsigned short* wlAll = usw + M4;            // lo (only Wo slot used)
    unsigned short* xh = usw + 2 * M4;           // x hi (later AOh)
    unsigned short* xl = usw + 3 * M4;           // later AOl
    unsigned short* Qh = usw + 4 * M4;
    unsigned short* Kh = usw + 5 * M4;
    unsigned short* Vh = usw + 6 * M4;
    float* ct = (float*)(usw + 7 * M4);
    float* st_ = ct + (size_t)Sc * 32;
    unsigned short* AOh = xh;   // x dead after QKV GEMM
    unsigned short* AOl = xl;

    // 1. RoPE table
    rope_table<<<dim3((Sc * 32) / 256), dim3(256), 0, stream>>>(ct, st_);
    // 2. convert x + weights to bf16 (Wo keeps hi/lo)
    split_xw<<<dim3(4096, 5), dim3(256), 0, stream>>>(x, Wq, Wk, Wv, Wo, xh, whAll, wlAll);
    // 3. QKV projections (1-product bf16, dbuf) with fused epilogues
    gemm_qkv<<<dim3(32, 8, 3), dim3(256), 0, stream>>>(
        xh, whAll, Qh, Kh, Vh, ct, st_);
    // 4. attention (64q/block, 4 blocks/CU, register-resident P) -> AOh/AOl
    attn7<<<dim3(1024), dim3(128), 0, stream>>>(Qh, Kh, Vh, AOh, AOl);
    // 5. output projection (3-product, 128x128 tiles)
    gemm_out<<<dim3(32, 8), dim3(256), 0, stream>>>(
        AOh, AOl, whAll + 3 * (1 << 20), wlAll + 3 * (1 << 20), out);
}